// Round 2
// 438.102 us; speedup vs baseline: 1.0148x; 1.0148x over previous
//
#include <hip/hip_runtime.h>
#include <cstdint>

// FirstEncoder: B=16 S=512 D=1024 H=16 L=128 V=32000, DH=64.
// Faithful: raw-reshape head split (head (b,h) = contiguous [512,64] block of
// the flat [8192,1024] buffer), score scale 1/32 (DH/2), FFN residual f+f=2f.

typedef __bf16 bf16;
typedef __bf16 bf16x8 __attribute__((ext_vector_type(8)));
typedef __bf16 bf16x4 __attribute__((ext_vector_type(4)));
typedef float f32x4 __attribute__((ext_vector_type(4)));

#define MFMA16(a, b, c) __builtin_amdgcn_mfma_f32_16x16x32_bf16((a), (b), (c), 0, 0, 0)

#if __has_builtin(__builtin_amdgcn_exp2f)
#define EXP2F(x) __builtin_amdgcn_exp2f(x)
#else
#define EXP2F(x) exp2f(x)
#endif

// async 16B global->LDS (lane i lands at wave-uniform base + i*16)
__device__ __forceinline__ void async16(const bf16* g, bf16* l) {
  __builtin_amdgcn_global_load_lds(
      (const __attribute__((address_space(1))) unsigned int*)g,
      (__attribute__((address_space(3))) unsigned int*)l, 16, 0, 0);
}

// counted waits, pinned against compiler reordering (memory clobber + sched fence)
#define VMWAIT(N)                                        \
  do {                                                   \
    asm volatile("s_waitcnt vmcnt(" #N ")" ::: "memory"); \
    __builtin_amdgcn_sched_barrier(0);                   \
  } while (0)
#define BAR() __builtin_amdgcn_s_barrier()

// ---------------------------------------------------------------------------
// 8x fused weight transpose + f32->bf16. All have K=1024 rows; N = 1024 for
// the six D x D weights, 128 for Wmu/Wsig. Wt[n*1024 + k] = W[k*N + n].
struct TP8 {
  const float* src[8];
  bf16* dst[8];
  int ncol[8];
};
__global__ __launch_bounds__(256) void transpose8_kernel(TP8 p) {
  const int z = blockIdx.z;
  const int N = p.ncol[z];
  const int tk = blockIdx.x * 64, tn = blockIdx.y * 64;
  if (tn >= N) return;
  const float* __restrict__ W = p.src[z];
  bf16* __restrict__ Wt = p.dst[z];
  __shared__ float tile[64][65];
  const int a = threadIdx.x >> 6, b = threadIdx.x & 63;
#pragma unroll
  for (int i = 0; i < 16; ++i) {
    int k = a + i * 4;
    tile[k][b] = W[(size_t)(tk + k) * N + tn + b];
  }
  __syncthreads();
#pragma unroll
  for (int i = 0; i < 16; ++i) {
    int n = a + i * 4;
    Wt[(size_t)(tn + n) * 1024 + tk + b] = (bf16)tile[b][n];
  }
}

// ---------------------------------------------------------------------------
// Fused embed (*32 + posenc) + LayerNorm1 -> bf16 h1.
// Wave-per-row: 4 rows/block, 16 elems/lane, pure shuffle reduce (no barrier).
__global__ __launch_bounds__(256) void embed_ln_kernel(const int* __restrict__ x,
                                                       const float* __restrict__ emb,
                                                       const float* __restrict__ g,
                                                       const float* __restrict__ be,
                                                       bf16* __restrict__ obf) {
  const int w = threadIdx.x >> 6, lane = threadIdx.x & 63;
  const int row = blockIdx.x * 4 + w;
  const int s = row & 511;
  const int t = x[row];
  const int c0 = lane * 16;
  const float* er = emb + (size_t)t * 1024 + c0;
  float o[16];
#pragma unroll
  for (int i = 0; i < 4; ++i) {
    const float4 e = *(const float4*)(er + i * 4);
    o[i * 4 + 0] = e.x; o[i * 4 + 1] = e.y; o[i * 4 + 2] = e.z; o[i * 4 + 3] = e.w;
  }
#pragma unroll
  for (int p = 0; p < 8; ++p) {
    const int cc = c0 + 2 * p;
    const float freq = __expf((float)cc * (-9.210340371976184f / 1024.0f));
    const float ang = (float)s * freq;
    o[2 * p] = o[2 * p] * 32.0f + __sinf(ang);
    o[2 * p + 1] = o[2 * p + 1] * 32.0f + __cosf(ang);
  }
  float sm = 0.f, q = 0.f;
#pragma unroll
  for (int j = 0; j < 16; ++j) { sm += o[j]; q += o[j] * o[j]; }
#pragma unroll
  for (int off = 1; off < 64; off <<= 1) {
    sm += __shfl_xor(sm, off);
    q += __shfl_xor(q, off);
  }
  const float mean = sm * (1.0f / 1024.0f);
  const float var = q * (1.0f / 1024.0f) - mean * mean;
  const float rstd = rsqrtf(var + 1e-5f);
  bf16 ob[16];
#pragma unroll
  for (int i = 0; i < 4; ++i) {
    const float4 gv = *(const float4*)(g + c0 + i * 4);
    const float4 bv = *(const float4*)(be + c0 + i * 4);
    const float gvv[4] = {gv.x, gv.y, gv.z, gv.w};
    const float bvv[4] = {bv.x, bv.y, bv.z, bv.w};
#pragma unroll
    for (int j = 0; j < 4; ++j)
      ob[i * 4 + j] = (bf16)((o[i * 4 + j] - mean) * rstd * gvv[j] + bvv[j]);
  }
  bf16* dst = obf + (size_t)row * 1024 + c0;
  *(uint4*)dst = *(const uint4*)&ob[0];
  *(uint4*)(dst + 8) = *(const uint4*)&ob[8];
}

// ---------------------------------------------------------------------------
// LayerNorm over D=1024, bf16 in -> bf16 out. Wave-per-row, no barrier.
__global__ __launch_bounds__(256) void ln_kernel(const bf16* __restrict__ in,
                                                 const float* __restrict__ g,
                                                 const float* __restrict__ be,
                                                 bf16* __restrict__ obf) {
  const int w = threadIdx.x >> 6, lane = threadIdx.x & 63;
  const int row = blockIdx.x * 4 + w;
  const int c0 = lane * 16;
  const bf16* src = in + (size_t)row * 1024 + c0;
  const bf16x8 v0 = *(const bf16x8*)src;
  const bf16x8 v1 = *(const bf16x8*)(src + 8);
  float v[16];
#pragma unroll
  for (int j = 0; j < 8; ++j) { v[j] = (float)v0[j]; v[8 + j] = (float)v1[j]; }
  float s = 0.f, q = 0.f;
#pragma unroll
  for (int j = 0; j < 16; ++j) { s += v[j]; q += v[j] * v[j]; }
#pragma unroll
  for (int off = 1; off < 64; off <<= 1) {
    s += __shfl_xor(s, off);
    q += __shfl_xor(q, off);
  }
  const float mean = s * (1.0f / 1024.0f);
  const float var = q * (1.0f / 1024.0f) - mean * mean;
  const float rstd = rsqrtf(var + 1e-5f);
  bf16 ob[16];
#pragma unroll
  for (int i = 0; i < 4; ++i) {
    const float4 gv = *(const float4*)(g + c0 + i * 4);
    const float4 bv = *(const float4*)(be + c0 + i * 4);
    const float gvv[4] = {gv.x, gv.y, gv.z, gv.w};
    const float bvv[4] = {bv.x, bv.y, bv.z, bv.w};
#pragma unroll
    for (int j = 0; j < 4; ++j)
      ob[i * 4 + j] = (bf16)((v[i * 4 + j] - mean) * rstd * gvv[j] + bvv[j]);
  }
  bf16* dst = obf + (size_t)row * 1024 + c0;
  *(uint4*)dst = *(const uint4*)&ob[0];
  *(uint4*)(dst + 8) = *(const uint4*)&ob[8];
}

// ---------------------------------------------------------------------------
// 8-phase counted-vmcnt GEMM (m201-style schedule, re-parameterized):
//   BM=128, BN=256, BK=64, 512 threads (8 waves as 2M x 4N), wave tile 64x64.
//   LDS 96KB: Asm 2x[128x64], Bsm 2x[256x64]  -> 1 block/CU, 8 waves/CU.
//   Grids: DxD -> (64,4)=256 blocks = 1/CU; QKV -> (64,12)=768 = 3 full rounds.
// Per iteration: compute tile e=2i from buf0 (ph1-4) and o=2i+1 from buf1
// (ph5-8); stage B0e'@ph3 B1e'@ph4 Ae'@ph5 B0o'@ph7 {B1o',Ao'}@ph8.
// vmcnt ledger (2 loads per 16KB half per thread, uniform across waves):
//   enter iter: 6 outstanding (odd tile -> buf1)
//   ph3 +2 (=8), ph4 +2 (=10) then vmcnt(4) retires odd tile -> buf1 ready
//   ph5 +2 (=6), ph7 +2 (=8), ph8 +4 (=12) then vmcnt(6) retires even tile
//   -> buf0 ready; 6 remain (odd tile). Invariant holds.
// Reads of a buffer always follow a barrier that follows every wave's wait.
// MODE 1: bf16 out = acc + b0 + resid(bf16)         (Wo)
// MODE 2: bf16 out = leaky_relu(acc + b0)           (W1)
// MODE 3: bf16 out = 2*(acc + b0)                   (W2, f+f)
// MODE 6: bf16 out routed to o0/o1/o2 by n-part     (fused QKV, N=3072)
__device__ __forceinline__ void ld_frags2(const bf16* sm, int rbase, int l15,
                                          int quad, bf16x8 out[2][2]) {
#pragma unroll
  for (int f = 0; f < 2; ++f) {
    const int row = rbase + f * 16 + l15;
    const int rx = row & 7;
#pragma unroll
    for (int h = 0; h < 2; ++h) {
      const int c = (h * 4 + quad) ^ rx;
      out[f][h] = *(const bf16x8*)(sm + (row * 8 + c) * 8);
    }
  }
}

template <int MQ, int NQ>
__device__ __forceinline__ void mma8(const bf16x8 aF[2][2], const bf16x8 bF[2][2],
                                     f32x4 acc[4][4]) {
  __builtin_amdgcn_s_setprio(1);
#pragma unroll
  for (int h = 0; h < 2; ++h)
#pragma unroll
    for (int m2 = 0; m2 < 2; ++m2)
#pragma unroll
      for (int n2 = 0; n2 < 2; ++n2)
        acc[MQ * 2 + m2][NQ * 2 + n2] =
            MFMA16(aF[m2][h], bF[n2][h], acc[MQ * 2 + m2][NQ * 2 + n2]);
  __builtin_amdgcn_s_setprio(0);
}

template <int MODE>
__global__ __launch_bounds__(512, 2) void gemm8_kernel(
    const bf16* __restrict__ A, const bf16* __restrict__ Bt,
    const float* __restrict__ b0f, const float* __restrict__ b1f,
    const float* __restrict__ b2f,
    bf16* __restrict__ o0, bf16* __restrict__ o1, bf16* __restrict__ o2,
    const bf16* __restrict__ residb,
    int M, int N, int K) {
  (void)M;
  __shared__ __attribute__((aligned(16))) bf16 Asm[2][128 * 64];
  __shared__ __attribute__((aligned(16))) bf16 Bsm[2][256 * 64];
  const int tid = threadIdx.x;
  const int wv = tid >> 6, lane = tid & 63;
  const int quad = lane >> 4, l15 = lane & 15;
  const int wm = wv & 1, wn = wv >> 1;
  const int m0 = blockIdx.x * 128, n0 = blockIdx.y * 256;

  f32x4 acc[4][4];
#pragma unroll
  for (int i = 0; i < 4; ++i)
#pragma unroll
    for (int j = 0; j < 4; ++j) acc[i][j] = {0.f, 0.f, 0.f, 0.f};

  // staging slots: 1024 slots/half (16KB), 2 per thread. XOR chunk swizzle on
  // the GLOBAL source (dest stays linear: global_load_lds constraint, rule 21).
  size_t aoff[2], boff[2];
  int slds[2];
#pragma unroll
  for (int i = 0; i < 2; ++i) {
    const int s = tid + i * 512;
    const int r = s >> 3, c = (s & 7) ^ (r & 7);
    aoff[i] = (size_t)(m0 + r) * K + c * 8;
    boff[i] = (size_t)(n0 + r) * K + c * 8;
    slds[i] = s * 8;
  }
  auto stageA = [&](int buf, int t) {
#pragma unroll
    for (int i = 0; i < 2; ++i) async16(A + aoff[i] + t * 64, &Asm[buf][slds[i]]);
  };
  auto stageB = [&](int buf, int hh, int t) {
    const size_t ho = (size_t)hh * 128 * K;
    const int hl = hh * 8192;
#pragma unroll
    for (int i = 0; i < 2; ++i)
      async16(Bt + boff[i] + ho + t * 64, &Bsm[buf][hl + slds[i]]);
  };

  // prologue: stage tiles 0 (buf0) and 1 (buf1); vmcnt(6) -> tile0 complete.
  stageB(0, 0, 0); stageB(0, 1, 0); stageA(0, 0);
  stageB(1, 0, 1); stageB(1, 1, 1); stageA(1, 1);
  VMWAIT(6);
  BAR();

  bf16x8 aF[2][2], bF0[2][2], bF1[2][2];
  const int am0 = wm * 64, bn0 = wn * 64;

  auto phases = [&](int ne, int no, bool hn) {
    // ph1: quad (m0,n0) of buf0
    ld_frags2(&Asm[0][0], am0, l15, quad, aF);
    ld_frags2(&Bsm[0][0], bn0, l15, quad, bF0);
    BAR();
    mma8<0, 0>(aF, bF0, acc);
    BAR();
    // ph2: (m0,n1)
    ld_frags2(&Bsm[0][0], bn0 + 32, l15, quad, bF1);
    BAR();
    mma8<0, 1>(aF, bF1, acc);
    BAR();
    // ph3: (m1,n1); stage B-half0 of next-even tile into buf0 (free since ph2)
    ld_frags2(&Asm[0][0], am0 + 32, l15, quad, aF);
    if (hn) stageB(0, 0, ne);
    BAR();
    mma8<1, 1>(aF, bF1, acc);
    BAR();
    // ph4: (m1,n0); stage B-half1(ne); vmcnt -> buf1 (tile o) complete
    if (hn) stageB(0, 1, ne);
    BAR();
    mma8<1, 0>(aF, bF0, acc);
    if (hn) { VMWAIT(4); } else { VMWAIT(0); }
    BAR();
    // ph5: (m0,n0) of buf1; stage A(ne) into buf0 (A free since ph3)
    ld_frags2(&Asm[1][0], am0, l15, quad, aF);
    ld_frags2(&Bsm[1][0], bn0, l15, quad, bF0);
    if (hn) stageA(0, ne);
    BAR();
    mma8<0, 0>(aF, bF0, acc);
    BAR();
    // ph6: (m0,n1)
    ld_frags2(&Bsm[1][0], bn0 + 32, l15, quad, bF1);
    BAR();
    mma8<0, 1>(aF, bF1, acc);
    BAR();
    // ph7: (m1,n1); stage B-half0 of next-odd tile into buf1
    ld_frags2(&Asm[1][0], am0 + 32, l15, quad, aF);
    if (hn) stageB(1, 0, no);
    BAR();
    mma8<1, 1>(aF, bF1, acc);
    BAR();
    // ph8: (m1,n0); stage B-half1(no)+A(no); vmcnt(6) -> buf0 (tile ne) ready
    if (hn) { stageB(1, 1, no); stageA(1, no); }
    BAR();
    mma8<1, 0>(aF, bF0, acc);
    if (hn) { VMWAIT(6); }
    BAR();
  };

  const int nIter = K >> 7;  // two 64-K-tiles per iteration
  for (int it = 0; it + 1 < nIter; ++it) phases(2 * it + 2, 2 * it + 3, true);
  phases(0, 0, false);  // peeled last iteration: no stages, full drain @ph4

  const int part = (MODE == 6) ? ((int)blockIdx.y >> 2) : 0;
  bf16* ob = o0;
  const float* bp = b0f;
  if constexpr (MODE == 6) {
    ob = (part == 0) ? o0 : (part == 1 ? o1 : o2);
    bp = (part == 0) ? b0f : (part == 1 ? b1f : b2f);
  }
#pragma unroll
  for (int ni = 0; ni < 4; ++ni) {
    const int col = n0 + wn * 64 + ni * 16 + l15;
    const int cl = (MODE == 6) ? (col - part * 1024) : col;
    const float bv = bp[cl];
#pragma unroll
    for (int mi = 0; mi < 4; ++mi) {
#pragma unroll
      for (int r = 0; r < 4; ++r) {
        const int row = m0 + wm * 64 + mi * 16 + quad * 4 + r;
        float v = acc[mi][ni][r] + bv;
        if constexpr (MODE == 1) {
          const size_t idx = (size_t)row * N + col;
          o0[idx] = (bf16)(v + (float)residb[idx]);
        } else if constexpr (MODE == 2) {
          o0[(size_t)row * N + col] = (bf16)(v > 0.f ? v : 0.01f * v);
        } else if constexpr (MODE == 3) {
          o0[(size_t)row * N + col] = (bf16)(2.0f * v);
        } else {  // MODE 6
          ob[(size_t)row * 1024 + cl] = (bf16)v;
        }
      }
    }
  }
}

// ---------------------------------------------------------------------------
// mu|sig GEMM: C[8192,256] f32 = A[8192,1024] @ wmsT^T + bias(mu|sig).
// 64x128 tile, grid (128,2) = 256 blocks (1/CU).
__global__ __launch_bounds__(256) void gemm_musig(const bf16* __restrict__ A,
                                                  const bf16* __restrict__ Bt,
                                                  const float* __restrict__ bmu,
                                                  const float* __restrict__ bsig,
                                                  float* __restrict__ of) {
  constexpr int BK = 64;
  __shared__ __attribute__((aligned(16))) bf16 Asm[2][64 * BK];
  __shared__ __attribute__((aligned(16))) bf16 Bsm[2][128 * BK];
  const int tid = threadIdx.x;
  const int wv = tid >> 6, lane = tid & 63;
  const int quad = lane >> 4, l15 = lane & 15;
  const int m0 = blockIdx.x * 64, n0 = blockIdx.y * 128;
  const int wm = wv & 1, wn = wv >> 1;

  f32x4 acc[2][4];
#pragma unroll
  for (int i = 0; i < 2; ++i)
#pragma unroll
    for (int j = 0; j < 4; ++j) acc[i][j] = {0.f, 0.f, 0.f, 0.f};

  const bf16* Aglb[2];
  int asoff[2];
#pragma unroll
  for (int i = 0; i < 2; ++i) {
    const int s = tid + i * 256;
    const int row = s >> 3, col = (s & 7) ^ (row & 7);
    Aglb[i] = A + (size_t)(m0 + row) * 1024 + col * 8;
    asoff[i] = s * 8;
  }
  const bf16* Bglb[4];
  int bsoff[4];
#pragma unroll
  for (int i = 0; i < 4; ++i) {
    const int s = tid + i * 256;
    const int row = s >> 3, col = (s & 7) ^ (row & 7);
    Bglb[i] = Bt + (size_t)(n0 + row) * 1024 + col * 8;
    bsoff[i] = s * 8;
  }

#pragma unroll
  for (int i = 0; i < 2; ++i) async16(Aglb[i], &Asm[0][asoff[i]]);
#pragma unroll
  for (int i = 0; i < 4; ++i) async16(Bglb[i], &Bsm[0][bsoff[i]]);
  __syncthreads();

  for (int k = 0; k < 16; ++k) {
    const int cur = k & 1, nxt = cur ^ 1;
    bf16x8 af[2][2], bfr[4][2];
#pragma unroll
    for (int mi = 0; mi < 2; ++mi) {
      const int row = wm * 32 + mi * 16 + l15;
#pragma unroll
      for (int h = 0; h < 2; ++h) {
        const int pos = (h * 4 + quad) ^ (row & 7);
        af[mi][h] = *(const bf16x8*)(&Asm[cur][(row * 8 + pos) * 8]);
      }
    }
#pragma unroll
    for (int ni = 0; ni < 4; ++ni) {
      const int row = wn * 64 + ni * 16 + l15;
#pragma unroll
      for (int h = 0; h < 2; ++h) {
        const int pos = (h * 4 + quad) ^ (row & 7);
        bfr[ni][h] = *(const bf16x8*)(&Bsm[cur][(row * 8 + pos) * 8]);
      }
    }
    if (k + 1 < 16) {
      const int ko = (k + 1) * BK;
#pragma unroll
      for (int i = 0; i < 2; ++i) async16(Aglb[i] + ko, &Asm[nxt][asoff[i]]);
#pragma unroll
      for (int i = 0; i < 4; ++i) async16(Bglb[i] + ko, &Bsm[nxt][bsoff[i]]);
    }
#pragma unroll
    for (int h = 0; h < 2; ++h)
#pragma unroll
      for (int mi = 0; mi < 2; ++mi)
#pragma unroll
        for (int ni = 0; ni < 4; ++ni)
          acc[mi][ni] = MFMA16(af[mi][h], bfr[ni][h], acc[mi][ni]);
    __syncthreads();
  }

#pragma unroll
  for (int ni = 0; ni < 4; ++ni) {
    const int col = n0 + wn * 64 + ni * 16 + l15;
    const float bv = (col < 128) ? bmu[col] : bsig[col - 128];
#pragma unroll
    for (int mi = 0; mi < 2; ++mi) {
#pragma unroll
      for (int r = 0; r < 4; ++r) {
        const int row = m0 + wm * 32 + mi * 16 + quad * 4 + r;
        of[(size_t)row * 256 + col] = acc[mi][ni][r] + bv;
      }
    }
  }
}

// ---------------------------------------------------------------------------
// V transpose per head: Vb flat [256 bh][512 kv][64 d] -> VtG [256 bh][64 d][512 kv]
__global__ __launch_bounds__(256) void vtrans_kernel(const bf16* __restrict__ Vb,
                                                     bf16* __restrict__ VtG) {
  __shared__ float t[64][65];
  const int bh = blockIdx.x, kt = blockIdx.y;
  const int tid = threadIdx.x;
  const bf16* src = Vb + (size_t)bh * 32768 + (size_t)kt * 4096;
#pragma unroll
  for (int i = 0; i < 2; ++i) {
    int s = i * 256 + tid;
    int r = s >> 3, c = (s & 7) * 8;
    bf16x8 v = *(const bf16x8*)(src + (size_t)s * 8);
#pragma unroll
    for (int j = 0; j < 8; ++j) t[r][c + j] = (float)v[j];
  }
  __syncthreads();
  bf16* dst = VtG + (size_t)bh * 32768 + kt * 64;
#pragma unroll
  for (int i = 0; i < 2; ++i) {
    int s = i * 256 + tid;
    int d = s >> 3, kc = (s & 7) * 8;
    bf16 tmp[8];
#pragma unroll
    for (int j = 0; j < 8; ++j) tmp[j] = (bf16)t[kc + j][d];
    *(uint4*)(dst + (size_t)d * 512 + kc) = *(const uint4*)tmp;
  }
}

// ---------------------------------------------------------------------------
// Flash-style attention. grid (256 bh, 4 qblk), 256 threads (4 waves).
// No-max softmax (|score/32| small): p = exp2(score * log2e/32) via Q prescale.
__global__ __launch_bounds__(256) void attn_kernel(const bf16* __restrict__ Qg,
                                                   const bf16* __restrict__ Kg,
                                                   const bf16* __restrict__ Vt,
                                                   bf16* __restrict__ ctx) {
  __shared__ __attribute__((aligned(16))) bf16 Ksm[128 * 64];
  __shared__ __attribute__((aligned(16))) bf16 Vsm[64 * 128];
  __shared__ __attribute__((aligned(16))) bf16 Psm[4][16 * 128];
  const int tid = threadIdx.x;
  const int w = tid >> 6, lane = tid & 63;
  const int quad = lane >> 4, l15 = lane & 15;
  const int bh = blockIdx.x;
  const size_t base = (size_t)bh * 32768;
  const bf16* Vth = Vt + base;
  const int qbase = blockIdx.y * 128 + w * 32;
  const f32x4 fz = {0.f, 0.f, 0.f, 0.f};

  bf16x8 a[2][2];
#pragma unroll
  for (int qt = 0; qt < 2; ++qt)
#pragma unroll
    for (int hf = 0; hf < 2; ++hf) {
      bf16x8 tq = *(const bf16x8*)(Qg + base +
                   (size_t)(qbase + qt * 16 + l15) * 64 + hf * 32 + quad * 8);
#pragma unroll
      for (int e = 0; e < 8; ++e) tq[e] = (bf16)((float)tq[e] * 0.045111758f);
      a[qt][hf] = tq;
    }

  f32x4 o[2][4];
  float l_i[2][4];
#pragma unroll
  for (int qt = 0; qt < 2; ++qt)
#pragma unroll
    for (int i = 0; i < 4; ++i) { o[qt][i] = fz; l_i[qt][i] = 0.f; }

  for (int kv0 = 0; kv0 < 512; kv0 += 128) {
#pragma unroll
    for (int i = 0; i < 4; ++i) {
      int s = i * 256 + tid;
      int r = s >> 3, c = (s & 7) ^ (r & 7);
      async16(Kg + base + (size_t)(kv0 + r) * 64 + c * 8, &Ksm[s * 8]);
    }
#pragma unroll
    for (int i = 0; i < 4; ++i) {
      int s = i * 256 + tid;
      int d = s >> 4, cs = s & 15;
      int c = (cs & 8) | ((cs & 7) ^ (d & 7));
      async16(Vth + (size_t)d * 512 + kv0 + c * 8, &Vsm[s * 8]);
    }
    __syncthreads();

    f32x4 sc[2][8];
#pragma unroll
    for (int j = 0; j < 8; ++j) {
      const int n = j * 16 + l15;
      const bf16x8 k0 = *(const bf16x8*)(&Ksm[(n * 8 + (quad ^ (n & 7))) * 8]);
      const bf16x8 k1 = *(const bf16x8*)(&Ksm[(n * 8 + ((4 + quad) ^ (n & 7))) * 8]);
      sc[0][j] = MFMA16(a[0][0], k0, fz);
      sc[0][j] = MFMA16(a[0][1], k1, sc[0][j]);
      sc[1][j] = MFMA16(a[1][0], k0, fz);
      sc[1][j] = MFMA16(a[1][1], k1, sc[1][j]);
    }

    bf16* ps = &Psm[w][0];
#pragma unroll
    for (int qt = 0; qt < 2; ++qt) {
#pragma unroll
      for (int r = 0; r < 4; ++r) {
        const int prow = quad * 4 + r;
        float sum = 0.f;
#pragma unroll
        for (int j = 0; j < 8; ++j) {
          const float p = EXP2F(sc[qt][j][r]);
          sum += p;
          const int col = j * 16 + l15;
          const int cc = col >> 3;
          const int ccs = (cc & 8) | ((cc & 7) ^ (prow & 7));
          ps[prow * 128 + ccs * 8 + (col & 7)] = (bf16)p;
        }
        l_i[qt][r] += sum;
      }
#pragma unroll
      for (int c32 = 0; c32 < 4; ++c32) {
        const int pc = c32 * 4 + quad;
        const int pcs = (pc & 8) | ((pc & 7) ^ (l15 & 7));
        const bf16x8 pf = *(const bf16x8*)(ps + l15 * 128 + pcs * 8);
#pragma unroll
        for (int ni = 0; ni < 4; ++ni) {
          const int d = ni * 16 + l15;
          const int vcs = (pc & 8) | ((pc & 7) ^ (d & 7));
          const bf16x8 vf = *(const bf16x8*)(&Vsm[(d * 16 + vcs) * 8]);
          o[qt][ni] = MFMA16(pf, vf, o[qt][ni]);
        }
      }
    }
    __syncthreads();
  }

#pragma unroll
  for (int qt = 0; qt < 2; ++qt) {
#pragma unroll
    for (int r = 0; r < 4; ++r) {
      float l = l_i[qt][r];
      l += __shfl_xor(l, 1);
      l += __shfl_xor(l, 2);
      l += __shfl_xor(l, 4);
      l += __shfl_xor(l, 8);
      const float inv = 1.0f / l;
#pragma unroll
      for (int ni = 0; ni < 4; ++ni)
        ctx[base + (size_t)(qbase + qt * 16 + quad * 4 + r) * 64 + ni * 16 + l15]
            = (bf16)(o[qt][ni][r] * inv);
    }
  }
}

// ---------------------------------------------------------------------------
// z = mu + exp(sig_raw) * eps from fused [8192,256] mu|sig buffer.
__global__ __launch_bounds__(256) void final_kernel(const float* __restrict__ musg,
                                                    const float* __restrict__ eps,
                                                    float* __restrict__ z) {
  const int i = blockIdx.x * 256 + threadIdx.x;
  const int row = i >> 5;
  const int c = (i & 31) * 4;
  const float4 m = *(const float4*)(musg + (size_t)row * 256 + c);
  const float4 s = *(const float4*)(musg + (size_t)row * 256 + 128 + c);
  const float4 e = *(const float4*)(eps + (size_t)row * 128 + c);
  float4 r;
  r.x = m.x + __expf(s.x) * e.x;
  r.y = m.y + __expf(s.y) * e.y;
  r.z = m.z + __expf(s.z) * e.z;
  r.w = m.w + __expf(s.w) * e.w;
  *(float4*)(z + (size_t)row * 128 + c) = r;
}

// ---------------------------------------------------------------------------
extern "C" void kernel_launch(void* const* d_in, const int* in_sizes, int n_in,
                              void* d_out, int out_size, void* d_ws, size_t ws_size,
                              hipStream_t stream) {
  (void)in_sizes; (void)n_in; (void)out_size; (void)ws_size;
  const int* x = (const int*)d_in[0];
  const float* emb = (const float*)d_in[1];
  const float* Wq = (const float*)d_in[2];
  const float* bq = (const float*)d_in[3];
  const float* Wk = (const float*)d_in[4];
  const float* bkb = (const float*)d_in[5];
  const float* Wv = (const float*)d_in[6];
  const float* bv = (const float*)d_in[7];
  const float* Wo = (const float*)d_in[8];
  const float* bo = (const float*)d_in[9];
  const float* g1 = (const float*)d_in[10];
  const float* be1 = (const float*)d_in[11];
  const float* W1 = (const float*)d_in[12];
  const float* bf1 = (const float*)d_in[13];
  const float* W2 = (const float*)d_in[14];
  const float* bf2 = (const float*)d_in[15];
  const float* g2 = (const float*)d_in[16];
  const float* be2 = (const float*)d_in[17];
  const float* g3 = (const float*)d_in[18];
  const float* be3 = (const float*)d_in[19];
  const float* Wmu = (const float*)d_in[20];
  const float* bmu = (const float*)d_in[21];
  const float* Wsig = (const float*)d_in[22];
  const float* bsig = (const float*)d_in[23];
  const float* eps = (const float*)d_in[24];
  float* z = (float*)d_out;

  const int M = 8192, D = 1024;
  char* ws = (char*)d_ws;
  size_t off = 0;
  auto alloc = [&](size_t b) {
    char* p = ws + off;
    off += (b + 255) & ~(size_t)255;
    return p;
  };
  bf16* wqkvT = (bf16*)alloc((size_t)3072 * 1024 * 2);  // [wq^T; wk^T; wv^T]
  bf16* woT = (bf16*)alloc((size_t)1024 * 1024 * 2);
  bf16* w1T = (bf16*)alloc((size_t)1024 * 1024 * 2);
  bf16* w2T = (bf16*)alloc((size_t)1024 * 1024 * 2);
  bf16* wmsT = (bf16*)alloc((size_t)256 * 1024 * 2);    // [Wmu^T ; Wsig^T]
  bf16* hb = (bf16*)alloc((size_t)M * D * 2);           // h1 (resid for Wo)
  bf16* Qb = (bf16*)alloc((size_t)M * D * 2);
  bf16* Kb = (bf16*)alloc((size_t)M * D * 2);
  bf16* Vb = (bf16*)alloc((size_t)M * D * 2);
  bf16* VtG = (bf16*)alloc((size_t)M * D * 2);
  bf16* Cb = (bf16*)alloc((size_t)M * D * 2);           // ctx
  bf16* h2b = (bf16*)alloc((size_t)M * D * 2);
  bf16* h3b = (bf16*)alloc((size_t)M * D * 2);
  bf16* hidb = (bf16*)alloc((size_t)M * D * 2);
  bf16* h4b = (bf16*)alloc((size_t)M * D * 2);
  bf16* h5b = (bf16*)alloc((size_t)M * D * 2);
  float* musg = (float*)alloc((size_t)M * 256 * 4);     // [8192,256] f32

  dim3 b256(256);
  dim3 b512(512);
  TP8 tp;
  tp.src[0] = Wq;   tp.dst[0] = wqkvT;                        tp.ncol[0] = 1024;
  tp.src[1] = Wk;   tp.dst[1] = wqkvT + (size_t)1024 * 1024;  tp.ncol[1] = 1024;
  tp.src[2] = Wv;   tp.dst[2] = wqkvT + (size_t)2048 * 1024;  tp.ncol[2] = 1024;
  tp.src[3] = Wo;   tp.dst[3] = woT;                          tp.ncol[3] = 1024;
  tp.src[4] = W1;   tp.dst[4] = w1T;                          tp.ncol[4] = 1024;
  tp.src[5] = W2;   tp.dst[5] = w2T;                          tp.ncol[5] = 1024;
  tp.src[6] = Wmu;  tp.dst[6] = wmsT;                         tp.ncol[6] = 128;
  tp.src[7] = Wsig; tp.dst[7] = wmsT + (size_t)128 * 1024;    tp.ncol[7] = 128;
  transpose8_kernel<<<dim3(16, 16, 8), b256, 0, stream>>>(tp);

  embed_ln_kernel<<<2048, b256, 0, stream>>>(x, emb, g1, be1, hb);  // h1

  // fused QKV: N=3072, outputs routed to Qb/Kb/Vb. 768 blocks = 3 full rounds.
  gemm8_kernel<6><<<dim3(64, 12), b512, 0, stream>>>(hb, wqkvT, bq, bkb, bv,
                                                     Qb, Kb, Vb, nullptr,
                                                     M, 3072, D);
  vtrans_kernel<<<dim3(256, 8), b256, 0, stream>>>(Vb, VtG);
  attn_kernel<<<dim3(256, 4), b256, 0, stream>>>(Qb, Kb, VtG, Cb);

  // DxD GEMMs: 256 blocks = exactly 1/CU, 8-phase counted-vmcnt schedule.
  gemm8_kernel<1><<<dim3(64, 4), b512, 0, stream>>>(Cb, woT, bo, nullptr, nullptr,
                                                    h2b, nullptr, nullptr, hb,
                                                    M, D, D);
  ln_kernel<<<2048, b256, 0, stream>>>(h2b, g2, be2, h3b);
  gemm8_kernel<2><<<dim3(64, 4), b512, 0, stream>>>(h3b, w1T, bf1, nullptr, nullptr,
                                                    hidb, nullptr, nullptr, nullptr,
                                                    M, D, D);
  gemm8_kernel<3><<<dim3(64, 4), b512, 0, stream>>>(hidb, w2T, bf2, nullptr, nullptr,
                                                    h4b, nullptr, nullptr, nullptr,
                                                    M, D, D);
  ln_kernel<<<2048, b256, 0, stream>>>(h4b, g3, be3, h5b);
  gemm_musig<<<dim3(128, 2), b256, 0, stream>>>(h5b, wmsT, bmu, bsig, musg);
  final_kernel<<<1024, b256, 0, stream>>>(musg, eps, z);
}